// Round 13
// baseline (473.995 us; speedup 1.0000x reference)
//
#include <hip/hip_runtime.h>
#include <hip/hip_bf16.h>
#include <math.h>

// Problem constants (B=1)
#define SEQ 1024
#define DM 512
#define NH 8
#define HD 64
#define NLAYER 4
#define DIN 128
#define DFF 2048
#define DOUT 390
#define ERROWS 2047  // 2*MAXS-1
#define NSPLIT 4     // flash split-K factor

using u16 = unsigned short;
typedef __attribute__((ext_vector_type(8))) short short8;
typedef __attribute__((ext_vector_type(4))) float f32x4;

__device__ inline u16 f2bf(float f){
  __hip_bfloat16 h = __float2bfloat16(f);
  return *(u16*)&h;
}
__device__ inline float bf2f(u16 u){
  __hip_bfloat16 h; *(u16*)&h = u;
  return __bfloat162float(h);
}

// ---------- fused one-time prep: converts + transposes, one launch ----------
__global__ __launch_bounds__(256)
void prep_k(const float* __restrict__ x, const float* __restrict__ Er,
            const float* __restrict__ bq, const float* __restrict__ bk,
            const float* __restrict__ bv,
            const float* __restrict__ emb_W, const float* __restrict__ Wq,
            const float* __restrict__ Wk, const float* __restrict__ Wv,
            const float* __restrict__ Wo, const float* __restrict__ W1,
            const float* __restrict__ W2, const float* __restrict__ Wi,
            const float* __restrict__ Wf,
            u16* __restrict__ xb, u16* __restrict__ erB,
            float* __restrict__ qkvbias,
            u16* __restrict__ embT, u16* __restrict__ wqkvT,
            u16* __restrict__ woT, u16* __restrict__ w1T,
            u16* __restrict__ w2T, u16* __restrict__ wiT,
            u16* __restrict__ wfT)
{
  __shared__ float Ls[64][65];
  int b = blockIdx.x;
  const int tid = threadIdx.x;

  if (b < 128){            // x convert
    int i = (b * 256 + tid) * 4;
    float4 v = *(const float4*)(x + i);
    xb[i+0]=f2bf(v.x); xb[i+1]=f2bf(v.y); xb[i+2]=f2bf(v.z); xb[i+3]=f2bf(v.w);
    return;
  }
  b -= 128;
  if (b < 512){            // Er convert
    int i = (b * 256 + tid) * 4;
    if (i < NLAYER * ERROWS * HD){
      float4 v = *(const float4*)(Er + i);
      erB[i+0]=f2bf(v.x); erB[i+1]=f2bf(v.y); erB[i+2]=f2bf(v.z); erB[i+3]=f2bf(v.w);
    }
    return;
  }
  b -= 512;
  if (b < 24){             // qkv bias concat
    int i = b * 256 + tid;
    int l = i / 1536, c = i - l * 1536;
    float v = (c < 512) ? bq[l * 512 + c]
            : (c < 1024) ? bk[l * 512 + c - 512]
                         : bv[l * 512 + c - 1024];
    qkvbias[i] = v;
    return;
  }
  b -= 24;

  const float* W; u16* WT; int K, N, k0, n0;
  if (b < 16){
    W = emb_W; WT = embT; K = DIN; N = DM;
    k0 = (b & 1) * 64; n0 = (b >> 1) * 64;
  } else if (b < 1040){
    int i = b - 16, fam = i >> 8, w2 = i & 255, z = w2 >> 6, t2 = w2 & 63;
    K = DM; N = DM; k0 = (t2 & 7) * 64; n0 = (t2 >> 3) * 64;
    const float* Wsrc = (fam == 0) ? Wq : (fam == 1) ? Wk : (fam == 2) ? Wv : Wo;
    W = Wsrc + (long)z * DM * DM;
    WT = (fam < 3) ? wqkvT + (long)z * 1536 * DM + (long)fam * 512 * DM
                   : woT + (long)z * DM * DM;
  } else if (b < 2064){
    int i = b - 1040, z = i >> 8, w2 = i & 255;
    K = DM; N = DFF; k0 = (w2 & 7) * 64; n0 = (w2 >> 3) * 64;
    W = W1 + (long)z * DM * DFF; WT = w1T + (long)z * DFF * DM;
  } else if (b < 3088){
    int i = b - 2064, z = i >> 8, w2 = i & 255;
    K = DFF; N = DM; k0 = (w2 & 31) * 64; n0 = (w2 >> 5) * 64;
    W = W2 + (long)z * DFF * DM; WT = w2T + (long)z * DM * DFF;
  } else if (b < 3216){
    int i = b - 3088;
    K = DM; N = 2 * DM; k0 = (i & 7) * 64; n0 = (i >> 3) * 64;
    W = Wi; WT = wiT;
  } else {
    int i = b - 3216;
    K = 2 * DM; N = DOUT; k0 = (i & 15) * 64; n0 = (i >> 4) * 64;
    W = Wf; WT = wfT;
  }

  const int cr = (tid & 15) * 4, rr0 = tid >> 4;
#pragma unroll
  for (int rr = 0; rr < 4; rr++){
    int row = rr0 + rr * 16;
    const float* wp = W + (size_t)(k0 + row) * N + n0 + cr;
#pragma unroll
    for (int j = 0; j < 4; j++)
      Ls[row][cr + j] = (n0 + cr + j < N) ? wp[j] : 0.f;
  }
  __syncthreads();
  const int nrow = tid >> 2, kc = (tid & 3) * 16;
  const bool valid = (n0 + nrow) < N;
  u16 buf[16];
#pragma unroll
  for (int j = 0; j < 16; j++)
    buf[j] = valid ? f2bf(Ls[kc + j][nrow]) : (u16)0;
  u16* out = WT + (size_t)(n0 + nrow) * K + k0 + kc;
  ((uint4*)out)[0] = ((uint4*)buf)[0];
  ((uint4*)out)[1] = ((uint4*)buf)[1];
}

// ---------- MFMA GEMM, 32x64 tile, BK=64, register-prefetch (R11) ----------
template<bool GELU, bool RES, bool BIAS, bool OUTBF>
__global__ __launch_bounds__(256)
void mgemm(const u16* __restrict__ A, const u16* __restrict__ B,
           const float* __restrict__ bias, const float* __restrict__ res,
           void* __restrict__ Cout, int N, int K,
           int lda, int ldb, int ldc)
{
  __shared__ u16 As[32][72];
  __shared__ u16 Bs[64][72];
  const int tid = threadIdx.x;
  const int row0 = blockIdx.y * 32, n0 = blockIdx.x * 64;
  const int w = tid >> 6, lane = tid & 63, m = lane & 15, quad = lane >> 4;
  const int rowg = w >> 1, colp = w & 1;
  const int ar = tid >> 3, akc = (tid & 7) * 8;
  const int br = tid >> 2, bkc = (tid & 3) * 16;

  f32x4 acc[2];
  acc[0] = (f32x4){0.f,0.f,0.f,0.f};
  acc[1] = (f32x4){0.f,0.f,0.f,0.f};

  uint4 pa  = *(const uint4*)&A[(long)(row0 + ar) * lda + akc];
  uint4 pb0 = *(const uint4*)&B[(long)(n0 + br) * ldb + bkc];
  uint4 pb1 = *(const uint4*)&B[(long)(n0 + br) * ldb + bkc + 8];

  for (int k0 = 0; k0 < K; k0 += 64){
    *(uint4*)&As[ar][akc]     = pa;
    *(uint4*)&Bs[br][bkc]     = pb0;
    *(uint4*)&Bs[br][bkc + 8] = pb1;
    __syncthreads();
    if (k0 + 64 < K){
      pa  = *(const uint4*)&A[(long)(row0 + ar) * lda + k0 + 64 + akc];
      pb0 = *(const uint4*)&B[(long)(n0 + br) * ldb + k0 + 64 + bkc];
      pb1 = *(const uint4*)&B[(long)(n0 + br) * ldb + k0 + 64 + bkc + 8];
    }
    short8 a0 = *(const short8*)&As[rowg * 16 + m][quad * 8];
    short8 a1 = *(const short8*)&As[rowg * 16 + m][32 + quad * 8];
#pragma unroll
    for (int c = 0; c < 2; c++){
      int colg = colp * 2 + c;
      short8 b0 = *(const short8*)&Bs[colg * 16 + m][quad * 8];
      short8 b1 = *(const short8*)&Bs[colg * 16 + m][32 + quad * 8];
      acc[c] = __builtin_amdgcn_mfma_f32_16x16x32_bf16(a0, b0, acc[c], 0, 0, 0);
      acc[c] = __builtin_amdgcn_mfma_f32_16x16x32_bf16(a1, b1, acc[c], 0, 0, 0);
    }
    __syncthreads();
  }

#pragma unroll
  for (int c = 0; c < 2; c++){
    int col = n0 + (colp * 2 + c) * 16 + m;
    if (col < N){
#pragma unroll
      for (int r = 0; r < 4; r++){
        int row = row0 + rowg * 16 + quad * 4 + r;
        float val = acc[c][r];
        if (BIAS) val += bias[col];
        if (RES)  val += res[(long)row * ldc + col];
        if (GELU) val = 0.5f * val * (1.f + erff(val * 0.70710678118f));
        if (OUTBF) ((u16*)Cout)[(long)row * ldc + col] = f2bf(val);
        else      ((float*)Cout)[(long)row * ldc + col] = val;
      }
    }
  }
}

// ---------- MFMA GEMM with fused-LN A-prologue: K=512, A resident in LDS ----------
// A = LN(Afp)*g+b rounded to bf16 (identical math/rounding to old ln_k path).
// Prologue once per block; K-loop streams only B. Out bf16 + bias (+gelu).
template<bool GELU>
__global__ __launch_bounds__(256)
void mgemm_ln(const float* __restrict__ Afp, const float* __restrict__ lng,
              const float* __restrict__ lnb, const u16* __restrict__ B,
              const float* __restrict__ bias, u16* __restrict__ Cout,
              int N, int ldc)
{
  __shared__ u16 As[32][520];   // row stride 1040B (16B-aligned, +4-word skew)
  __shared__ u16 Bs[64][72];
  const int tid = threadIdx.x;
  const int row0 = blockIdx.y * 32, n0 = blockIdx.x * 64;

  // ---- prologue: LN 32 rows into As (8 threads per row) ----
  {
    const int r = tid >> 3, cl = tid & 7;
    const float* xr = Afp + (long)(row0 + r) * 512;
    float4 va[8], vb[8];
    float s = 0.f, q = 0.f;
#pragma unroll
    for (int jj = 0; jj < 8; jj++){
      int c0 = cl * 8 + 64 * jj;
      va[jj] = *(const float4*)(xr + c0);
      vb[jj] = *(const float4*)(xr + c0 + 4);
      s += va[jj].x + va[jj].y + va[jj].z + va[jj].w
         + vb[jj].x + vb[jj].y + vb[jj].z + vb[jj].w;
      q += va[jj].x*va[jj].x + va[jj].y*va[jj].y + va[jj].z*va[jj].z + va[jj].w*va[jj].w
         + vb[jj].x*vb[jj].x + vb[jj].y*vb[jj].y + vb[jj].z*vb[jj].z + vb[jj].w*vb[jj].w;
    }
#pragma unroll
    for (int off = 1; off < 8; off <<= 1){
      s += __shfl_xor(s, off);
      q += __shfl_xor(q, off);
    }
    float mn = s * (1.f / 512.f);
    float inv = rsqrtf(q * (1.f / 512.f) - mn * mn + 1e-5f);
#pragma unroll
    for (int jj = 0; jj < 8; jj++){
      int c0 = cl * 8 + 64 * jj;
      float4 g0 = *(const float4*)(lng + c0), g1 = *(const float4*)(lng + c0 + 4);
      float4 b0 = *(const float4*)(lnb + c0), b1 = *(const float4*)(lnb + c0 + 4);
      u16 t2[8];
      t2[0] = f2bf((va[jj].x - mn) * inv * g0.x + b0.x);
      t2[1] = f2bf((va[jj].y - mn) * inv * g0.y + b0.y);
      t2[2] = f2bf((va[jj].z - mn) * inv * g0.z + b0.z);
      t2[3] = f2bf((va[jj].w - mn) * inv * g0.w + b0.w);
      t2[4] = f2bf((vb[jj].x - mn) * inv * g1.x + b1.x);
      t2[5] = f2bf((vb[jj].y - mn) * inv * g1.y + b1.y);
      t2[6] = f2bf((vb[jj].z - mn) * inv * g1.z + b1.z);
      t2[7] = f2bf((vb[jj].w - mn) * inv * g1.w + b1.w);
      *(uint4*)&As[r][c0] = *(uint4*)t2;
    }
  }

  const int w = tid >> 6, lane = tid & 63, m = lane & 15, quad = lane >> 4;
  const int rowg = w >> 1, colp = w & 1;
  const int br = tid >> 2, bkc = (tid & 3) * 16;

  f32x4 acc[2];
  acc[0] = (f32x4){0.f,0.f,0.f,0.f};
  acc[1] = (f32x4){0.f,0.f,0.f,0.f};

  uint4 pb0 = *(const uint4*)&B[(long)(n0 + br) * 512 + bkc];
  uint4 pb1 = *(const uint4*)&B[(long)(n0 + br) * 512 + bkc + 8];

  for (int k0 = 0; k0 < 512; k0 += 64){
    *(uint4*)&Bs[br][bkc]     = pb0;
    *(uint4*)&Bs[br][bkc + 8] = pb1;
    __syncthreads();    // first iter also covers As prologue
    if (k0 + 64 < 512){
      pb0 = *(const uint4*)&B[(long)(n0 + br) * 512 + k0 + 64 + bkc];
      pb1 = *(const uint4*)&B[(long)(n0 + br) * 512 + k0 + 64 + bkc + 8];
    }
    short8 a0 = *(const short8*)&As[rowg * 16 + m][k0 + quad * 8];
    short8 a1 = *(const short8*)&As[rowg * 16 + m][k0 + 32 + quad * 8];
#pragma unroll
    for (int c = 0; c < 2; c++){
      int colg = colp * 2 + c;
      short8 b0 = *(const short8*)&Bs[colg * 16 + m][quad * 8];
      short8 b1 = *(const short8*)&Bs[colg * 16 + m][32 + quad * 8];
      acc[c] = __builtin_amdgcn_mfma_f32_16x16x32_bf16(a0, b0, acc[c], 0, 0, 0);
      acc[c] = __builtin_amdgcn_mfma_f32_16x16x32_bf16(a1, b1, acc[c], 0, 0, 0);
    }
    __syncthreads();
  }

#pragma unroll
  for (int c = 0; c < 2; c++){
    int col = n0 + (colp * 2 + c) * 16 + m;
#pragma unroll
    for (int r = 0; r < 4; r++){
      int row = row0 + rowg * 16 + quad * 4 + r;
      float val = acc[c][r] + bias[col];
      if (GELU) val = 0.5f * val * (1.f + erff(val * 0.70710678118f));
      Cout[(long)row * ldc + col] = f2bf(val);
    }
  }
}

// ---------- Wo GEMM with fused split-combine A-prologue ----------
// A[r][c] = bf16( (1/Σ w_sp·l_sp) · Σ w_sp·Op[sp][h=c>>6][row][c&63] ), exact fcomb math.
// Out fp32 with bias + residual into hb.
__global__ __launch_bounds__(256)
void wo_comb(const float* __restrict__ Op, const float* __restrict__ ml,
             const u16* __restrict__ B, const float* __restrict__ bias,
             float* __restrict__ hb)
{
  __shared__ u16 As[32][520];
  __shared__ u16 Bs[64][72];
  const int tid = threadIdx.x;
  const int row0 = blockIdx.y * 32, n0 = blockIdx.x * 64;

  // ---- prologue: combine 4 split partials into As ----
  {
    const int r = tid >> 3, cl = tid & 7;
    const int s = row0 + r;
#pragma unroll
    for (int jj = 0; jj < 8; jj++){       // jj == head (c0 = cl*8 + 64*jj, cl*8<64)
      float mm[NSPLIT], ll[NSPLIT];
#pragma unroll
      for (int sp = 0; sp < NSPLIT; sp++){
        long bix = (((long)sp * NH + jj) * SEQ + s) * 2;
        mm[sp] = ml[bix]; ll[sp] = ml[bix + 1];
      }
      float ms = fmaxf(fmaxf(mm[0], mm[1]), fmaxf(mm[2], mm[3]));
      float wsp[NSPLIT], lsum = 0.f;
#pragma unroll
      for (int sp = 0; sp < NSPLIT; sp++){
        wsp[sp] = __expf(mm[sp] - ms);
        lsum += wsp[sp] * ll[sp];
      }
      float winv = 1.f / lsum;
      float o[8];
#pragma unroll
      for (int j = 0; j < 8; j++) o[j] = 0.f;
#pragma unroll
      for (int sp = 0; sp < NSPLIT; sp++){
        const float* op = Op + (((long)sp * NH + jj) * SEQ + s) * HD + cl * 8;
        float4 u0 = *(const float4*)(op);
        float4 u1 = *(const float4*)(op + 4);
        o[0] += wsp[sp] * u0.x; o[1] += wsp[sp] * u0.y;
        o[2] += wsp[sp] * u0.z; o[3] += wsp[sp] * u0.w;
        o[4] += wsp[sp] * u1.x; o[5] += wsp[sp] * u1.y;
        o[6] += wsp[sp] * u1.z; o[7] += wsp[sp] * u1.w;
      }
      u16 t2[8];
#pragma unroll
      for (int j = 0; j < 8; j++) t2[j] = f2bf(o[j] * winv);
      *(uint4*)&As[r][cl * 8 + 64 * jj] = *(uint4*)t2;
    }
  }

  const int w = tid >> 6, lane = tid & 63, m = lane & 15, quad = lane >> 4;
  const int rowg = w >> 1, colp = w & 1;
  const int br = tid >> 2, bkc = (tid & 3) * 16;

  f32x4 acc[2];
  acc[0] = (f32x4){0.f,0.f,0.f,0.f};
  acc[1] = (f32x4){0.f,0.f,0.f,0.f};

  uint4 pb0 = *(const uint4*)&B[(long)(n0 + br) * 512 + bkc];
  uint4 pb1 = *(const uint4*)&B[(long)(n0 + br) * 512 + bkc + 8];

  for (int k0 = 0; k0 < 512; k0 += 64){
    *(uint4*)&Bs[br][bkc]     = pb0;
    *(uint4*)&Bs[br][bkc + 8] = pb1;
    __syncthreads();
    if (k0 + 64 < 512){
      pb0 = *(const uint4*)&B[(long)(n0 + br) * 512 + k0 + 64 + bkc];
      pb1 = *(const uint4*)&B[(long)(n0 + br) * 512 + k0 + 64 + bkc + 8];
    }
    short8 a0 = *(const short8*)&As[rowg * 16 + m][k0 + quad * 8];
    short8 a1 = *(const short8*)&As[rowg * 16 + m][k0 + 32 + quad * 8];
#pragma unroll
    for (int c = 0; c < 2; c++){
      int colg = colp * 2 + c;
      short8 b0 = *(const short8*)&Bs[colg * 16 + m][quad * 8];
      short8 b1 = *(const short8*)&Bs[colg * 16 + m][32 + quad * 8];
      acc[c] = __builtin_amdgcn_mfma_f32_16x16x32_bf16(a0, b0, acc[c], 0, 0, 0);
      acc[c] = __builtin_amdgcn_mfma_f32_16x16x32_bf16(a1, b1, acc[c], 0, 0, 0);
    }
    __syncthreads();
  }

#pragma unroll
  for (int c = 0; c < 2; c++){
    int col = n0 + (colp * 2 + c) * 16 + m;
#pragma unroll
    for (int r = 0; r < 4; r++){
      int row = row0 + rowg * 16 + quad * 4 + r;
      float val = acc[c][r] + bias[col] + hb[(long)row * DM + col];
      hb[(long)row * DM + col] = val;
    }
  }
}

// ---------- split-K flash attention (R11, unchanged) ----------
__global__ __launch_bounds__(256)
void flash_k(const u16* __restrict__ qkv, const u16* __restrict__ ErB,
             float* __restrict__ Op, float* __restrict__ ml)
{
  __shared__ u16 Qs[64][72];
  __shared__ u16 Ks[64][72];
  __shared__ u16 VsT[64][72];
  __shared__ u16 Es[128][72];
  __shared__ u16 Ts[64][136];
  __shared__ u16 Ps[64][72];

  const int tid = threadIdx.x;
  const int s0 = blockIdx.x * 64, hh = blockIdx.y, sp = blockIdx.z;
  const int w = tid >> 6, lane = tid & 63, m = lane & 15, quad = lane >> 4;

  {
    const int r = tid >> 2, kc = (tid & 3) * 16;
    const u16* qp = qkv + (size_t)(s0 + r) * 1536 + hh * HD + kc;
    *(uint4*)&Qs[r][kc]     = *(const uint4*)&qp[0];
    *(uint4*)&Qs[r][kc + 8] = *(const uint4*)&qp[8];
  }
  __syncthreads();

  const short8 a0 = *(const short8*)&Qs[w * 16 + m][quad * 8];
  const short8 a1 = *(const short8*)&Qs[w * 16 + m][32 + quad * 8];

  f32x4 accO[4];
#pragma unroll
  for (int c = 0; c < 4; c++) accO[c] = (f32x4){0.f, 0.f, 0.f, 0.f};
  float mrun[4], lrun[4];
#pragma unroll
  for (int r = 0; r < 4; r++){ mrun[r] = -1e30f; lrun[r] = 0.f; }

  const int tbeg = sp * (SEQ / NSPLIT), tend = tbeg + SEQ / NSPLIT;
  for (int t0 = tbeg; t0 < tend; t0 += 64){
    __syncthreads();
    {
      const int r = tid >> 2, kc = (tid & 3) * 16;
      const u16* kp = qkv + (size_t)(t0 + r) * 1536 + 512 + hh * HD + kc;
      *(uint4*)&Ks[r][kc]     = *(const uint4*)&kp[0];
      *(uint4*)&Ks[r][kc + 8] = *(const uint4*)&kp[8];
      const u16* vp = qkv + (size_t)(t0 + r) * 1536 + 1024 + hh * HD + kc;
      uint4 v0 = *(const uint4*)&vp[0];
      uint4 v1 = *(const uint4*)&vp[8];
      const u16* pv0 = (const u16*)&v0;
      const u16* pv1 = (const u16*)&v1;
#pragma unroll
      for (int j = 0; j < 8; j++) VsT[kc + j][r]     = pv0[j];
#pragma unroll
      for (int j = 0; j < 8; j++) VsT[kc + 8 + j][r] = pv1[j];
      const int rb = s0 - t0 + 960;
      for (int idx = tid; idx < 127 * 8; idx += 256){
        int er = idx >> 3, ekc = (idx & 7) * 8;
        *(uint4*)&Es[er][ekc] = *(const uint4*)&ErB[(size_t)(rb + er) * HD + ekc];
      }
      if (tid < 8){ uint4 z = {0,0,0,0}; *(uint4*)&Es[127][tid * 8] = z; }
    }
    __syncthreads();

    f32x4 qk[4], tt[8];
#pragma unroll
    for (int c = 0; c < 4; c++) qk[c] = (f32x4){0.f,0.f,0.f,0.f};
#pragma unroll
    for (int c = 0; c < 8; c++) tt[c] = (f32x4){0.f,0.f,0.f,0.f};
#pragma unroll
    for (int c = 0; c < 4; c++){
      short8 b0 = *(const short8*)&Ks[c * 16 + m][quad * 8];
      short8 b1 = *(const short8*)&Ks[c * 16 + m][32 + quad * 8];
      qk[c] = __builtin_amdgcn_mfma_f32_16x16x32_bf16(a0, b0, qk[c], 0, 0, 0);
      qk[c] = __builtin_amdgcn_mfma_f32_16x16x32_bf16(a1, b1, qk[c], 0, 0, 0);
    }
#pragma unroll
    for (int c = 0; c < 8; c++){
      short8 b0 = *(const short8*)&Es[c * 16 + m][quad * 8];
      short8 b1 = *(const short8*)&Es[c * 16 + m][32 + quad * 8];
      tt[c] = __builtin_amdgcn_mfma_f32_16x16x32_bf16(a0, b0, tt[c], 0, 0, 0);
      tt[c] = __builtin_amdgcn_mfma_f32_16x16x32_bf16(a1, b1, tt[c], 0, 0, 0);
    }
#pragma unroll
    for (int c = 0; c < 8; c++)
#pragma unroll
      for (int r = 0; r < 4; r++)
        Ts[w * 16 + quad * 4 + r][c * 16 + m] = f2bf(tt[c][r]);
    __syncthreads();

    float sv[4][4];
#pragma unroll
    for (int c = 0; c < 4; c++){
      int j = c * 16 + m;
#pragma unroll
      for (int r = 0; r < 4; r++){
        int i = w * 16 + quad * 4 + r;
        sv[c][r] = qk[c][r] * 0.125f + bf2f(Ts[i][i - j + 63]);
      }
    }
    float alpha[4];
#pragma unroll
    for (int r = 0; r < 4; r++){
      float rmax = fmaxf(fmaxf(sv[0][r], sv[1][r]), fmaxf(sv[2][r], sv[3][r]));
#pragma unroll
      for (int off = 1; off < 16; off <<= 1)
        rmax = fmaxf(rmax, __shfl_xor(rmax, off));
      float mnew = fmaxf(mrun[r], rmax);
      alpha[r] = __expf(mrun[r] - mnew);
      mrun[r] = mnew;
      float rsum = 0.f;
#pragma unroll
      for (int c = 0; c < 4; c++){
        float pv = __expf(sv[c][r] - mnew);
        sv[c][r] = pv;
        rsum += pv;
      }
#pragma unroll
      for (int off = 1; off < 16; off <<= 1)
        rsum += __shfl_xor(rsum, off);
      lrun[r] = lrun[r] * alpha[r] + rsum;
    }
#pragma unroll
    for (int c = 0; c < 4; c++)
#pragma unroll
      for (int r = 0; r < 4; r++)
        accO[c][r] *= alpha[r];
#pragma unroll
    for (int c = 0; c < 4; c++)
#pragma unroll
      for (int r = 0; r < 4; r++)
        Ps[w * 16 + quad * 4 + r][c * 16 + m] = f2bf(sv[c][r]);
    __syncthreads();

    short8 pa0 = *(const short8*)&Ps[w * 16 + m][quad * 8];
    short8 pa1 = *(const short8*)&Ps[w * 16 + m][32 + quad * 8];
#pragma unroll
    for (int c = 0; c < 4; c++){
      short8 b0 = *(const short8*)&VsT[c * 16 + m][quad * 8];
      short8 b1 = *(const short8*)&VsT[c * 16 + m][32 + quad * 8];
      accO[c] = __builtin_amdgcn_mfma_f32_16x16x32_bf16(pa0, b0, accO[c], 0, 0, 0);
      accO[c] = __builtin_amdgcn_mfma_f32_16x16x32_bf16(pa1, b1, accO[c], 0, 0, 0);
    }
  }

  const long base = ((long)sp * NH + hh) * SEQ;
#pragma unroll
  for (int c = 0; c < 4; c++){
#pragma unroll
    for (int r = 0; r < 4; r++){
      int row = s0 + w * 16 + quad * 4 + r;
      Op[(base + row) * HD + c * 16 + m] = accO[c][r];
    }
  }
  if (m == 0){
#pragma unroll
    for (int r = 0; r < 4; r++){
      int row = s0 + w * 16 + quad * 4 + r;
      ml[(base + row) * 2 + 0] = mrun[r];
      ml[(base + row) * 2 + 1] = lrun[r];
    }
  }
}

extern "C" void kernel_launch(void* const* d_in, const int* in_sizes, int n_in,
                              void* d_out, int out_size, void* d_ws, size_t ws_size,
                              hipStream_t stream) {
  const float* x     = (const float*)d_in[0];
  const float* emb_W = (const float*)d_in[1];
  const float* emb_b = (const float*)d_in[2];
  const float* Wq    = (const float*)d_in[3];
  const float* bq    = (const float*)d_in[4];
  const float* Wk    = (const float*)d_in[5];
  const float* bk    = (const float*)d_in[6];
  const float* Wv    = (const float*)d_in[7];
  const float* bv    = (const float*)d_in[8];
  const float* Wo    = (const float*)d_in[9];
  const float* bo    = (const float*)d_in[10];
  const float* Er    = (const float*)d_in[11];
  const float* ln1_g = (const float*)d_in[12];
  const float* ln1_b = (const float*)d_in[13];
  const float* W1    = (const float*)d_in[14];
  const float* b1    = (const float*)d_in[15];
  const float* W2    = (const float*)d_in[16];
  const float* b2    = (const float*)d_in[17];
  const float* ln2_g = (const float*)d_in[18];
  const float* ln2_b = (const float*)d_in[19];
  const float* lnf_g = (const float*)d_in[20];
  const float* lnf_b = (const float*)d_in[21];
  const float* Wi    = (const float*)d_in[22];
  const float* bi    = (const float*)d_in[23];
  const float* Wf    = (const float*)d_in[24];
  const float* bfin  = (const float*)d_in[25];

  // ---- workspace carve ----
  u16* p = (u16*)d_ws;
  u16* xb    = p; p += SEQ * DIN;
  u16* embT  = p; p += DM * DIN;
  u16* wqkvT = p; p += (size_t)NLAYER * 1536 * DM;
  u16* woT   = p; p += (size_t)NLAYER * DM * DM;
  u16* w1T   = p; p += (size_t)NLAYER * DFF * DM;
  u16* w2T   = p; p += (size_t)NLAYER * DM * DFF;
  u16* wiT   = p; p += (size_t)(2 * DM) * DM;
  u16* wfT   = p; p += (size_t)448 * (2 * DM);
  u16* erB   = p; p += (size_t)NLAYER * ERROWS * HD;
  u16* qkvb  = p; p += (size_t)SEQ * 1536;
  u16* mid   = p; p += (size_t)SEQ * DFF;
  float* qkvbias = (float*)p;
  float* hb  = qkvbias + NLAYER * 1536;
  float* Op  = hb + SEQ * DM;
  float* mlb = Op + (size_t)NSPLIT * NH * SEQ * HD;

  dim3 blk(256);

  prep_k<<<3992, blk, 0, stream>>>(
      x, Er, bq, bk, bv, emb_W, Wq, Wk, Wv, Wo, W1, W2, Wi, Wf,
      xb, erB, qkvbias, embT, wqkvT, woT, w1T, w2T, wiT, wfT);

  dim3 g512(8, 32), gqkv(24, 32), gff(32, 32), gwi(16, 32), gout(7, 32);
  dim3 gfl(16, NH, NSPLIT);

  // embedding: hb = xb @ embT + emb_b (fp32)
  mgemm<false, false, true, false><<<g512, blk, 0, stream>>>(
      xb, embT, emb_b, nullptr, hb, DM, DIN, DIN, DIN, DM);

  for (int l = 0; l < NLAYER; l++) {
    const u16* wqkvT_l = wqkvT + (size_t)l * 1536 * DM;
    const u16* woT_l   = woT + (size_t)l * DM * DM;
    const u16* w1T_l   = w1T + (size_t)l * DFF * DM;
    const u16* w2T_l   = w2T + (size_t)l * DM * DFF;
    const u16* erB_l   = erB + (size_t)l * ERROWS * HD;

    // LN1 + QKV (fused prologue)
    mgemm_ln<false><<<gqkv, blk, 0, stream>>>(
        hb, ln1_g + l * DM, ln1_b + l * DM, wqkvT_l, qkvbias + l * 1536,
        qkvb, 1536, 1536);

    flash_k<<<gfl, blk, 0, stream>>>(qkvb, erB_l, Op, mlb);

    // combine + Wo + residual (fused prologue)
    wo_comb<<<g512, blk, 0, stream>>>(Op, mlb, woT_l, bo + l * DM, hb);

    // LN2 + FFN1 + GELU (fused prologue)
    mgemm_ln<true><<<gff, blk, 0, stream>>>(
        hb, ln2_g + l * DM, ln2_b + l * DM, w1T_l, b1 + l * DFF,
        mid, DFF, DFF);

    mgemm<false, true, true, false><<<g512, blk, 0, stream>>>(
        mid, w2T_l, b2 + l * DM, hb, hb, DM, DFF, DFF, DFF, DM);
  }

  // LNf + Wi + GELU (fused prologue)
  mgemm_ln<true><<<gwi, blk, 0, stream>>>(
      hb, lnf_g, lnf_b, wiT, bi, mid, 2 * DM, 2 * DM);
  mgemm<false, false, true, false><<<gout, blk, 0, stream>>>(
      mid, wfT, bfin, nullptr, (float*)d_out, DOUT, 2 * DM, 2 * DM, 2 * DM, DOUT);
}

// Round 14
// 442.437 us; speedup vs baseline: 1.0713x; 1.0713x over previous
//
#include <hip/hip_runtime.h>
#include <hip/hip_bf16.h>
#include <math.h>

// Problem constants (B=1)
#define SEQ 1024
#define DM 512
#define NH 8
#define HD 64
#define NLAYER 4
#define DIN 128
#define DFF 2048
#define DOUT 390
#define ERROWS 2047  // 2*MAXS-1
#define NSPLIT 4     // flash split-K factor

using u16 = unsigned short;
typedef __attribute__((ext_vector_type(8))) short short8;
typedef __attribute__((ext_vector_type(4))) float f32x4;

__device__ inline u16 f2bf(float f){
  __hip_bfloat16 h = __float2bfloat16(f);
  return *(u16*)&h;
}
__device__ inline float bf2f(u16 u){
  __hip_bfloat16 h; *(u16*)&h = u;
  return __bfloat162float(h);
}

// ---------- fused one-time prep: converts + transposes, one launch ----------
__global__ __launch_bounds__(256)
void prep_k(const float* __restrict__ x, const float* __restrict__ Er,
            const float* __restrict__ bq, const float* __restrict__ bk,
            const float* __restrict__ bv,
            const float* __restrict__ emb_W, const float* __restrict__ Wq,
            const float* __restrict__ Wk, const float* __restrict__ Wv,
            const float* __restrict__ Wo, const float* __restrict__ W1,
            const float* __restrict__ W2, const float* __restrict__ Wi,
            const float* __restrict__ Wf,
            u16* __restrict__ xb, u16* __restrict__ erB,
            float* __restrict__ qkvbias,
            u16* __restrict__ embT, u16* __restrict__ wqkvT,
            u16* __restrict__ woT, u16* __restrict__ w1T,
            u16* __restrict__ w2T, u16* __restrict__ wiT,
            u16* __restrict__ wfT)
{
  __shared__ float Ls[64][65];
  int b = blockIdx.x;
  const int tid = threadIdx.x;

  if (b < 128){            // x convert
    int i = (b * 256 + tid) * 4;
    float4 v = *(const float4*)(x + i);
    xb[i+0]=f2bf(v.x); xb[i+1]=f2bf(v.y); xb[i+2]=f2bf(v.z); xb[i+3]=f2bf(v.w);
    return;
  }
  b -= 128;
  if (b < 512){            // Er convert
    int i = (b * 256 + tid) * 4;
    if (i < NLAYER * ERROWS * HD){
      float4 v = *(const float4*)(Er + i);
      erB[i+0]=f2bf(v.x); erB[i+1]=f2bf(v.y); erB[i+2]=f2bf(v.z); erB[i+3]=f2bf(v.w);
    }
    return;
  }
  b -= 512;
  if (b < 24){             // qkv bias concat
    int i = b * 256 + tid;
    int l = i / 1536, c = i - l * 1536;
    float v = (c < 512) ? bq[l * 512 + c]
            : (c < 1024) ? bk[l * 512 + c - 512]
                         : bv[l * 512 + c - 1024];
    qkvbias[i] = v;
    return;
  }
  b -= 24;

  const float* W; u16* WT; int K, N, k0, n0;
  if (b < 16){
    W = emb_W; WT = embT; K = DIN; N = DM;
    k0 = (b & 1) * 64; n0 = (b >> 1) * 64;
  } else if (b < 1040){
    int i = b - 16, fam = i >> 8, w2 = i & 255, z = w2 >> 6, t2 = w2 & 63;
    K = DM; N = DM; k0 = (t2 & 7) * 64; n0 = (t2 >> 3) * 64;
    const float* Wsrc = (fam == 0) ? Wq : (fam == 1) ? Wk : (fam == 2) ? Wv : Wo;
    W = Wsrc + (long)z * DM * DM;
    WT = (fam < 3) ? wqkvT + (long)z * 1536 * DM + (long)fam * 512 * DM
                   : woT + (long)z * DM * DM;
  } else if (b < 2064){
    int i = b - 1040, z = i >> 8, w2 = i & 255;
    K = DM; N = DFF; k0 = (w2 & 7) * 64; n0 = (w2 >> 3) * 64;
    W = W1 + (long)z * DM * DFF; WT = w1T + (long)z * DFF * DM;
  } else if (b < 3088){
    int i = b - 2064, z = i >> 8, w2 = i & 255;
    K = DFF; N = DM; k0 = (w2 & 31) * 64; n0 = (w2 >> 5) * 64;
    W = W2 + (long)z * DFF * DM; WT = w2T + (long)z * DM * DFF;
  } else if (b < 3216){
    int i = b - 3088;
    K = DM; N = 2 * DM; k0 = (i & 7) * 64; n0 = (i >> 3) * 64;
    W = Wi; WT = wiT;
  } else {
    int i = b - 3216;
    K = 2 * DM; N = DOUT; k0 = (i & 15) * 64; n0 = (i >> 4) * 64;
    W = Wf; WT = wfT;
  }

  const int cr = (tid & 15) * 4, rr0 = tid >> 4;
#pragma unroll
  for (int rr = 0; rr < 4; rr++){
    int row = rr0 + rr * 16;
    const float* wp = W + (size_t)(k0 + row) * N + n0 + cr;
#pragma unroll
    for (int j = 0; j < 4; j++)
      Ls[row][cr + j] = (n0 + cr + j < N) ? wp[j] : 0.f;
  }
  __syncthreads();
  const int nrow = tid >> 2, kc = (tid & 3) * 16;
  const bool valid = (n0 + nrow) < N;
  u16 buf[16];
#pragma unroll
  for (int j = 0; j < 16; j++)
    buf[j] = valid ? f2bf(Ls[kc + j][nrow]) : (u16)0;
  u16* out = WT + (size_t)(n0 + nrow) * K + k0 + kc;
  ((uint4*)out)[0] = ((uint4*)buf)[0];
  ((uint4*)out)[1] = ((uint4*)buf)[1];
}

// ---------- MFMA GEMM, 32x64 tile, BK=64, register-prefetch (R11) ----------
template<bool GELU, bool RES, bool BIAS, bool OUTBF>
__global__ __launch_bounds__(256)
void mgemm(const u16* __restrict__ A, const u16* __restrict__ B,
           const float* __restrict__ bias, const float* __restrict__ res,
           void* __restrict__ Cout, int N, int K,
           int lda, int ldb, int ldc)
{
  __shared__ u16 As[32][72];
  __shared__ u16 Bs[64][72];
  const int tid = threadIdx.x;
  const int row0 = blockIdx.y * 32, n0 = blockIdx.x * 64;
  const int w = tid >> 6, lane = tid & 63, m = lane & 15, quad = lane >> 4;
  const int rowg = w >> 1, colp = w & 1;
  const int ar = tid >> 3, akc = (tid & 7) * 8;
  const int br = tid >> 2, bkc = (tid & 3) * 16;

  f32x4 acc[2];
  acc[0] = (f32x4){0.f,0.f,0.f,0.f};
  acc[1] = (f32x4){0.f,0.f,0.f,0.f};

  uint4 pa  = *(const uint4*)&A[(long)(row0 + ar) * lda + akc];
  uint4 pb0 = *(const uint4*)&B[(long)(n0 + br) * ldb + bkc];
  uint4 pb1 = *(const uint4*)&B[(long)(n0 + br) * ldb + bkc + 8];

  for (int k0 = 0; k0 < K; k0 += 64){
    *(uint4*)&As[ar][akc]     = pa;
    *(uint4*)&Bs[br][bkc]     = pb0;
    *(uint4*)&Bs[br][bkc + 8] = pb1;
    __syncthreads();
    if (k0 + 64 < K){
      pa  = *(const uint4*)&A[(long)(row0 + ar) * lda + k0 + 64 + akc];
      pb0 = *(const uint4*)&B[(long)(n0 + br) * ldb + k0 + 64 + bkc];
      pb1 = *(const uint4*)&B[(long)(n0 + br) * ldb + k0 + 64 + bkc + 8];
    }
    short8 a0 = *(const short8*)&As[rowg * 16 + m][quad * 8];
    short8 a1 = *(const short8*)&As[rowg * 16 + m][32 + quad * 8];
#pragma unroll
    for (int c = 0; c < 2; c++){
      int colg = colp * 2 + c;
      short8 b0 = *(const short8*)&Bs[colg * 16 + m][quad * 8];
      short8 b1 = *(const short8*)&Bs[colg * 16 + m][32 + quad * 8];
      acc[c] = __builtin_amdgcn_mfma_f32_16x16x32_bf16(a0, b0, acc[c], 0, 0, 0);
      acc[c] = __builtin_amdgcn_mfma_f32_16x16x32_bf16(a1, b1, acc[c], 0, 0, 0);
    }
    __syncthreads();
  }

#pragma unroll
  for (int c = 0; c < 2; c++){
    int col = n0 + (colp * 2 + c) * 16 + m;
    if (col < N){
#pragma unroll
      for (int r = 0; r < 4; r++){
        int row = row0 + rowg * 16 + quad * 4 + r;
        float val = acc[c][r];
        if (BIAS) val += bias[col];
        if (RES)  val += res[(long)row * ldc + col];
        if (GELU) val = 0.5f * val * (1.f + erff(val * 0.70710678118f));
        if (OUTBF) ((u16*)Cout)[(long)row * ldc + col] = f2bf(val);
        else      ((float*)Cout)[(long)row * ldc + col] = val;
      }
    }
  }
}

// ---------- LayerNorm: wave-per-row shuffle (no barriers), 4 rows/block ----------
__global__ __launch_bounds__(256)
void ln_k(const float* __restrict__ x, const float* __restrict__ g,
          const float* __restrict__ b, u16* __restrict__ out)
{
  const int w = threadIdx.x >> 6, lane = threadIdx.x & 63;
  const int r = blockIdx.x * 4 + w;
  const float4* xr = (const float4*)(x + (long)r * DM + lane * 8);
  float4 v0 = xr[0], v1 = xr[1];
  float s = v0.x+v0.y+v0.z+v0.w + v1.x+v1.y+v1.z+v1.w;
  float q = v0.x*v0.x+v0.y*v0.y+v0.z*v0.z+v0.w*v0.w
          + v1.x*v1.x+v1.y*v1.y+v1.z*v1.z+v1.w*v1.w;
#pragma unroll
  for (int off = 1; off < 64; off <<= 1){
    s += __shfl_xor(s, off);
    q += __shfl_xor(q, off);
  }
  float mn = s * (1.f / DM);
  float inv = rsqrtf(q * (1.f / DM) - mn * mn + 1e-5f);
  const float4* gp = (const float4*)(g + lane * 8);
  const float4* bp = (const float4*)(b + lane * 8);
  float4 g0 = gp[0], g1 = gp[1], b0 = bp[0], b1 = bp[1];
  u16 tmp[8];
  tmp[0] = f2bf((v0.x - mn) * inv * g0.x + b0.x);
  tmp[1] = f2bf((v0.y - mn) * inv * g0.y + b0.y);
  tmp[2] = f2bf((v0.z - mn) * inv * g0.z + b0.z);
  tmp[3] = f2bf((v0.w - mn) * inv * g0.w + b0.w);
  tmp[4] = f2bf((v1.x - mn) * inv * g1.x + b1.x);
  tmp[5] = f2bf((v1.y - mn) * inv * g1.y + b1.y);
  tmp[6] = f2bf((v1.z - mn) * inv * g1.z + b1.z);
  tmp[7] = f2bf((v1.w - mn) * inv * g1.w + b1.w);
  *(uint4*)(out + (long)r * DM + lane * 8) = *(uint4*)tmp;
}

// ---------- split-K flash attention (R11, unchanged) ----------
__global__ __launch_bounds__(256)
void flash_k(const u16* __restrict__ qkv, const u16* __restrict__ ErB,
             float* __restrict__ Op, float* __restrict__ ml)
{
  __shared__ u16 Qs[64][72];
  __shared__ u16 Ks[64][72];
  __shared__ u16 VsT[64][72];
  __shared__ u16 Es[128][72];
  __shared__ u16 Ts[64][136];
  __shared__ u16 Ps[64][72];

  const int tid = threadIdx.x;
  const int s0 = blockIdx.x * 64, hh = blockIdx.y, sp = blockIdx.z;
  const int w = tid >> 6, lane = tid & 63, m = lane & 15, quad = lane >> 4;

  {
    const int r = tid >> 2, kc = (tid & 3) * 16;
    const u16* qp = qkv + (size_t)(s0 + r) * 1536 + hh * HD + kc;
    *(uint4*)&Qs[r][kc]     = *(const uint4*)&qp[0];
    *(uint4*)&Qs[r][kc + 8] = *(const uint4*)&qp[8];
  }
  __syncthreads();

  const short8 a0 = *(const short8*)&Qs[w * 16 + m][quad * 8];
  const short8 a1 = *(const short8*)&Qs[w * 16 + m][32 + quad * 8];

  f32x4 accO[4];
#pragma unroll
  for (int c = 0; c < 4; c++) accO[c] = (f32x4){0.f, 0.f, 0.f, 0.f};
  float mrun[4], lrun[4];
#pragma unroll
  for (int r = 0; r < 4; r++){ mrun[r] = -1e30f; lrun[r] = 0.f; }

  const int tbeg = sp * (SEQ / NSPLIT), tend = tbeg + SEQ / NSPLIT;
  for (int t0 = tbeg; t0 < tend; t0 += 64){
    __syncthreads();
    {
      const int r = tid >> 2, kc = (tid & 3) * 16;
      const u16* kp = qkv + (size_t)(t0 + r) * 1536 + 512 + hh * HD + kc;
      *(uint4*)&Ks[r][kc]     = *(const uint4*)&kp[0];
      *(uint4*)&Ks[r][kc + 8] = *(const uint4*)&kp[8];
      const u16* vp = qkv + (size_t)(t0 + r) * 1536 + 1024 + hh * HD + kc;
      uint4 v0 = *(const uint4*)&vp[0];
      uint4 v1 = *(const uint4*)&vp[8];
      const u16* pv0 = (const u16*)&v0;
      const u16* pv1 = (const u16*)&v1;
#pragma unroll
      for (int j = 0; j < 8; j++) VsT[kc + j][r]     = pv0[j];
#pragma unroll
      for (int j = 0; j < 8; j++) VsT[kc + 8 + j][r] = pv1[j];
      const int rb = s0 - t0 + 960;
      for (int idx = tid; idx < 127 * 8; idx += 256){
        int er = idx >> 3, ekc = (idx & 7) * 8;
        *(uint4*)&Es[er][ekc] = *(const uint4*)&ErB[(size_t)(rb + er) * HD + ekc];
      }
      if (tid < 8){ uint4 z = {0,0,0,0}; *(uint4*)&Es[127][tid * 8] = z; }
    }
    __syncthreads();

    f32x4 qk[4], tt[8];
#pragma unroll
    for (int c = 0; c < 4; c++) qk[c] = (f32x4){0.f,0.f,0.f,0.f};
#pragma unroll
    for (int c = 0; c < 8; c++) tt[c] = (f32x4){0.f,0.f,0.f,0.f};
#pragma unroll
    for (int c = 0; c < 4; c++){
      short8 b0 = *(const short8*)&Ks[c * 16 + m][quad * 8];
      short8 b1 = *(const short8*)&Ks[c * 16 + m][32 + quad * 8];
      qk[c] = __builtin_amdgcn_mfma_f32_16x16x32_bf16(a0, b0, qk[c], 0, 0, 0);
      qk[c] = __builtin_amdgcn_mfma_f32_16x16x32_bf16(a1, b1, qk[c], 0, 0, 0);
    }
#pragma unroll
    for (int c = 0; c < 8; c++){
      short8 b0 = *(const short8*)&Es[c * 16 + m][quad * 8];
      short8 b1 = *(const short8*)&Es[c * 16 + m][32 + quad * 8];
      tt[c] = __builtin_amdgcn_mfma_f32_16x16x32_bf16(a0, b0, tt[c], 0, 0, 0);
      tt[c] = __builtin_amdgcn_mfma_f32_16x16x32_bf16(a1, b1, tt[c], 0, 0, 0);
    }
#pragma unroll
    for (int c = 0; c < 8; c++)
#pragma unroll
      for (int r = 0; r < 4; r++)
        Ts[w * 16 + quad * 4 + r][c * 16 + m] = f2bf(tt[c][r]);
    __syncthreads();

    float sv[4][4];
#pragma unroll
    for (int c = 0; c < 4; c++){
      int j = c * 16 + m;
#pragma unroll
      for (int r = 0; r < 4; r++){
        int i = w * 16 + quad * 4 + r;
        sv[c][r] = qk[c][r] * 0.125f + bf2f(Ts[i][i - j + 63]);
      }
    }
    float alpha[4];
#pragma unroll
    for (int r = 0; r < 4; r++){
      float rmax = fmaxf(fmaxf(sv[0][r], sv[1][r]), fmaxf(sv[2][r], sv[3][r]));
#pragma unroll
      for (int off = 1; off < 16; off <<= 1)
        rmax = fmaxf(rmax, __shfl_xor(rmax, off));
      float mnew = fmaxf(mrun[r], rmax);
      alpha[r] = __expf(mrun[r] - mnew);
      mrun[r] = mnew;
      float rsum = 0.f;
#pragma unroll
      for (int c = 0; c < 4; c++){
        float pv = __expf(sv[c][r] - mnew);
        sv[c][r] = pv;
        rsum += pv;
      }
#pragma unroll
      for (int off = 1; off < 16; off <<= 1)
        rsum += __shfl_xor(rsum, off);
      lrun[r] = lrun[r] * alpha[r] + rsum;
    }
#pragma unroll
    for (int c = 0; c < 4; c++)
#pragma unroll
      for (int r = 0; r < 4; r++)
        accO[c][r] *= alpha[r];
#pragma unroll
    for (int c = 0; c < 4; c++)
#pragma unroll
      for (int r = 0; r < 4; r++)
        Ps[w * 16 + quad * 4 + r][c * 16 + m] = f2bf(sv[c][r]);
    __syncthreads();

    short8 pa0 = *(const short8*)&Ps[w * 16 + m][quad * 8];
    short8 pa1 = *(const short8*)&Ps[w * 16 + m][32 + quad * 8];
#pragma unroll
    for (int c = 0; c < 4; c++){
      short8 b0 = *(const short8*)&VsT[c * 16 + m][quad * 8];
      short8 b1 = *(const short8*)&VsT[c * 16 + m][32 + quad * 8];
      accO[c] = __builtin_amdgcn_mfma_f32_16x16x32_bf16(pa0, b0, accO[c], 0, 0, 0);
      accO[c] = __builtin_amdgcn_mfma_f32_16x16x32_bf16(pa1, b1, accO[c], 0, 0, 0);
    }
  }

  const long base = ((long)sp * NH + hh) * SEQ;
#pragma unroll
  for (int c = 0; c < 4; c++){
#pragma unroll
    for (int r = 0; r < 4; r++){
      int row = s0 + w * 16 + quad * 4 + r;
      Op[(base + row) * HD + c * 16 + m] = accO[c][r];
    }
  }
  if (m == 0){
#pragma unroll
    for (int r = 0; r < 4; r++){
      int row = s0 + w * 16 + quad * 4 + r;
      ml[(base + row) * 2 + 0] = mrun[r];
      ml[(base + row) * 2 + 1] = lrun[r];
    }
  }
}

// combine split partials: 4 rows per block (R10-validated body)
__global__ __launch_bounds__(256)
void fcomb_k(const float* __restrict__ Op, const float* __restrict__ ml,
             u16* __restrict__ o)
{
  const int tid = threadIdx.x;
  const int hh = tid >> 5, c0 = (tid & 31) * 2;
#pragma unroll
  for (int i = 0; i < 4; i++){
    const int s = blockIdx.x * 4 + i;
    float mm[NSPLIT], ll[NSPLIT];
#pragma unroll
    for (int sp = 0; sp < NSPLIT; sp++){
      long b = (((long)sp * NH + hh) * SEQ + s) * 2;
      mm[sp] = ml[b]; ll[sp] = ml[b + 1];
    }
    float ms = fmaxf(fmaxf(mm[0], mm[1]), fmaxf(mm[2], mm[3]));
    float o0 = 0.f, o1 = 0.f, lsum = 0.f;
#pragma unroll
    for (int sp = 0; sp < NSPLIT; sp++){
      float wsp = __expf(mm[sp] - ms);
      lsum += wsp * ll[sp];
      const float* op = Op + (((long)sp * NH + hh) * SEQ + s) * HD + c0;
      o0 += wsp * op[0];
      o1 += wsp * op[1];
    }
    float inv = 1.f / lsum;
    o[(size_t)s * DM + hh * HD + c0]     = f2bf(o0 * inv);
    o[(size_t)s * DM + hh * HD + c0 + 1] = f2bf(o1 * inv);
  }
}

extern "C" void kernel_launch(void* const* d_in, const int* in_sizes, int n_in,
                              void* d_out, int out_size, void* d_ws, size_t ws_size,
                              hipStream_t stream) {
  const float* x     = (const float*)d_in[0];
  const float* emb_W = (const float*)d_in[1];
  const float* emb_b = (const float*)d_in[2];
  const float* Wq    = (const float*)d_in[3];
  const float* bq    = (const float*)d_in[4];
  const float* Wk    = (const float*)d_in[5];
  const float* bk    = (const float*)d_in[6];
  const float* Wv    = (const float*)d_in[7];
  const float* bv    = (const float*)d_in[8];
  const float* Wo    = (const float*)d_in[9];
  const float* bo    = (const float*)d_in[10];
  const float* Er    = (const float*)d_in[11];
  const float* ln1_g = (const float*)d_in[12];
  const float* ln1_b = (const float*)d_in[13];
  const float* W1    = (const float*)d_in[14];
  const float* b1    = (const float*)d_in[15];
  const float* W2    = (const float*)d_in[16];
  const float* b2    = (const float*)d_in[17];
  const float* ln2_g = (const float*)d_in[18];
  const float* ln2_b = (const float*)d_in[19];
  const float* lnf_g = (const float*)d_in[20];
  const float* lnf_b = (const float*)d_in[21];
  const float* Wi    = (const float*)d_in[22];
  const float* bi    = (const float*)d_in[23];
  const float* Wf    = (const float*)d_in[24];
  const float* bfin  = (const float*)d_in[25];

  // ---- workspace carve ----
  u16* p = (u16*)d_ws;
  u16* xb    = p; p += SEQ * DIN;
  u16* embT  = p; p += DM * DIN;
  u16* wqkvT = p; p += (size_t)NLAYER * 1536 * DM;
  u16* woT   = p; p += (size_t)NLAYER * DM * DM;
  u16* w1T   = p; p += (size_t)NLAYER * DFF * DM;
  u16* w2T   = p; p += (size_t)NLAYER * DM * DFF;
  u16* wiT   = p; p += (size_t)(2 * DM) * DM;
  u16* wfT   = p; p += (size_t)448 * (2 * DM);
  u16* erB   = p; p += (size_t)NLAYER * ERROWS * HD;
  u16* nb    = p; p += SEQ * DM;
  u16* qkvb  = p; p += (size_t)SEQ * 1536;
  u16* ob    = p; p += SEQ * DM;
  u16* mid   = p; p += (size_t)SEQ * DFF;
  float* qkvbias = (float*)p;
  float* hb  = qkvbias + NLAYER * 1536;
  float* Op  = hb + SEQ * DM;
  float* mlb = Op + (size_t)NSPLIT * NH * SEQ * HD;

  dim3 blk(256);

  prep_k<<<3992, blk, 0, stream>>>(
      x, Er, bq, bk, bv, emb_W, Wq, Wk, Wv, Wo, W1, W2, Wi, Wf,
      xb, erB, qkvbias, embT, wqkvT, woT, w1T, w2T, wiT, wfT);

  // grids: x = N/64, y = M/32 = 32
  dim3 g512(8, 32), gqkv(24, 32), gff(32, 32), gwi(16, 32), gout(7, 32);
  dim3 gfl(16, NH, NSPLIT);
  dim3 gln(SEQ / 4);

  // ---- embedding ----
  mgemm<false, false, true, false><<<g512, blk, 0, stream>>>(
      xb, embT, emb_b, nullptr, hb, DM, DIN, DIN, DIN, DM);

  for (int l = 0; l < NLAYER; l++) {
    const u16* wqkvT_l = wqkvT + (size_t)l * 1536 * DM;
    const u16* woT_l   = woT + (size_t)l * DM * DM;
    const u16* w1T_l   = w1T + (size_t)l * DFF * DM;
    const u16* w2T_l   = w2T + (size_t)l * DM * DFF;
    const u16* erB_l   = erB + (size_t)l * ERROWS * HD;

    ln_k<<<gln, blk, 0, stream>>>(hb, ln1_g + l * DM, ln1_b + l * DM, nb);
    mgemm<false, false, true, true><<<gqkv, blk, 0, stream>>>(
        nb, wqkvT_l, qkvbias + l * 1536, nullptr, qkvb, 1536, DM, DM, DM, 1536);

    flash_k<<<gfl, blk, 0, stream>>>(qkvb, erB_l, Op, mlb);
    fcomb_k<<<SEQ / 4, blk, 0, stream>>>(Op, mlb, ob);

    mgemm<false, true, true, false><<<g512, blk, 0, stream>>>(
        ob, woT_l, bo + l * DM, hb, hb, DM, DM, DM, DM, DM);

    ln_k<<<gln, blk, 0, stream>>>(hb, ln2_g + l * DM, ln2_b + l * DM, nb);
    mgemm<true, false, true, true><<<gff, blk, 0, stream>>>(
        nb, w1T_l, b1 + l * DFF, nullptr, mid, DFF, DM, DM, DM, DFF);
    mgemm<false, true, true, false><<<g512, blk, 0, stream>>>(
        mid, w2T_l, b2 + l * DM, hb, hb, DM, DFF, DFF, DFF, DM);
  }

  ln_k<<<gln, blk, 0, stream>>>(hb, lnf_g, lnf_b, nb);
  mgemm<true, false, true, true><<<gwi, blk, 0, stream>>>(
      nb, wiT, bi, nullptr, mid, 2 * DM, DM, DM, DM, 2 * DM);
  mgemm<false, false, true, false><<<gout, blk, 0, stream>>>(
      mid, wfT, bfin, nullptr, (float*)d_out, DOUT, 2 * DM, 2 * DM, 2 * DM, DOUT);
}